// Round 9
// baseline (474.853 us; speedup 1.0000x reference)
//
#include <hip/hip_runtime.h>
#include <math.h>

#define G_ 512
#define N_ 512
#define NN_ (G_*N_)
#define EG_ 8192
#define CIN_ 128
#define HID_ 32
#define K_ 20
#define LAT_ 65

// relative tie window: ~1.5 ulp of fp32 (2^-23 = 1.19e-7)
#define EPS_REL 1.8e-7f

// ---------------- CSR build v2: atomic count/place + per-bin sort ----------
__global__ __launch_bounds__(512) void csr2_kernel(const int* __restrict__ src,
                                                   const int* __restrict__ dst,
                                                   unsigned short* __restrict__ srcl,
                                                   int* __restrict__ gstart,
                                                   double* __restrict__ disd) {
    __shared__ int cnt[N_];
    __shared__ int startv[N_];
    __shared__ int tmpv[N_];
    __shared__ int cursor[N_];
    __shared__ unsigned short binE[EG_];
    int g = blockIdx.x, tid = threadIdx.x;
    const int* ds = dst + (size_t)g * EG_;
    const int* ss = src + (size_t)g * EG_;
    int nb = g * N_;

    cnt[tid] = 0;
    __syncthreads();
    for (int e = tid; e < EG_; e += 512) atomicAdd(&cnt[ds[e] - nb], 1);
    __syncthreads();

    startv[tid] = cnt[tid];
    __syncthreads();
    for (int off = 1; off < N_; off <<= 1) {
        tmpv[tid] = startv[tid] + (tid >= off ? startv[tid - off] : 0);
        __syncthreads();
        startv[tid] = tmpv[tid];
        __syncthreads();
    }

    int excl = startv[tid] - cnt[tid];
    cursor[tid] = excl;
    gstart[g * (N_ + 1) + tid] = excl;
    if (tid == 0) gstart[g * (N_ + 1) + N_] = EG_;
    disd[nb + tid] = 1.0 / sqrt((double)(cnt[tid] + 1));
    __syncthreads();

    for (int e = tid; e < EG_; e += 512) {
        int d = ds[e] - nb;
        int slot = atomicAdd(&cursor[d], 1);
        binE[slot] = (unsigned short)e;
    }
    __syncthreads();

    {
        int n = cnt[tid];
        for (int i = 1; i < n; ++i) {
            unsigned short key = binE[excl + i];
            int j = i - 1;
            while (j >= 0 && binE[excl + j] > key) {
                binE[excl + j + 1] = binE[excl + j];
                --j;
            }
            binE[excl + j + 1] = key;
        }
    }
    __syncthreads();

    for (int i = tid; i < EG_; i += 512) {
        int e = binE[i];
        srcl[(size_t)g * EG_ + i] = (unsigned short)(ss[e] - nb);
    }
}

// ---------------- fused GCN layer: h = x@W (fp64); agg; tanh ---------------
template <int CI>
__global__ __launch_bounds__(512) void gcn_kernel(const float* __restrict__ xin,
                                                  const float* __restrict__ W,
                                                  const float* __restrict__ bias,
                                                  const unsigned short* __restrict__ srcl,
                                                  const int* __restrict__ gstart,
                                                  const double* __restrict__ disd,
                                                  float* __restrict__ xout) {
    __shared__ double hd[N_][HID_];         // 128 KB
    __shared__ unsigned short ssrc[EG_];    // 16 KB
    __shared__ int sstart[N_ + 1];
    __shared__ double sdis[N_];
    int g = blockIdx.x, tid = threadIdx.x;
    size_t nbase = (size_t)g * N_;

    for (int i = tid; i < EG_; i += 512) ssrc[i] = srcl[(size_t)g * EG_ + i];
    for (int i = tid; i <= N_; i += 512) sstart[i] = gstart[g * (N_ + 1) + i];
    for (int i = tid; i < N_; i += 512) sdis[i] = disd[nbase + i];

    int o = tid & 31, grp = tid >> 5;
    int n0 = grp * 32;

    double acc[32];
#pragma unroll
    for (int j = 0; j < 32; ++j) acc[j] = 0.0;
    const float* xbase = xin + (nbase + n0) * CI;
    for (int c = 0; c < CI; ++c) {
        double w = (double)W[c * HID_ + o];
#pragma unroll
        for (int j = 0; j < 32; ++j)
            acc[j] = fma((double)xbase[(size_t)j * CI + c], w, acc[j]);
    }
#pragma unroll
    for (int j = 0; j < 32; ++j) hd[n0 + j][o] = acc[j];
    __syncthreads();

    double b = (double)bias[o];
    for (int j = 0; j < 32; ++j) {
        int n = n0 + j;
        int e0 = sstart[n], e1 = sstart[n + 1];
        double a = 0.0;
        for (int e = e0; e < e1; ++e) {
            int s = ssrc[e];
            a += hd[s][o] * sdis[s];
        }
        double dn = sdis[n];
        double v = a * dn + hd[n][o] * dn * dn + b;
        xout[(nbase + n) * HID_ + o] = tanhf((float)v);
    }
}

// ---------------- layer 3 (32 -> 1): fp32 key = round(fp64 tanh) -----------
__global__ __launch_bounds__(512) void gcn3_kernel(const float* __restrict__ xin,
                                                   const float* __restrict__ W2,
                                                   const float* __restrict__ b2,
                                                   const unsigned short* __restrict__ srcl,
                                                   const int* __restrict__ gstart,
                                                   const double* __restrict__ disd,
                                                   float* __restrict__ x3f) {
    __shared__ double h1[N_];
    __shared__ unsigned short ssrc[EG_];
    __shared__ int sstart[N_ + 1];
    __shared__ double sdis[N_];
    int g = blockIdx.x, tid = threadIdx.x;
    size_t nbase = (size_t)g * N_;

    for (int i = tid; i < EG_; i += 512) ssrc[i] = srcl[(size_t)g * EG_ + i];
    for (int i = tid; i <= N_; i += 512) sstart[i] = gstart[g * (N_ + 1) + i];
    int n = tid;
    {
        double a = 0.0;
#pragma unroll
        for (int c = 0; c < HID_; ++c)
            a = fma((double)xin[(nbase + n) * HID_ + c], (double)W2[c], a);
        h1[n] = a;
        sdis[n] = disd[nbase + n];
    }
    __syncthreads();

    int e0 = sstart[n], e1 = sstart[n + 1];
    double a = 0.0;
    for (int e = e0; e < e1; ++e) {
        int s = ssrc[e];
        a += h1[s] * sdis[s];
    }
    double dn = sdis[n];
    double v = a * dn + h1[n] * dn * dn + (double)b2[0];
    x3f[nbase + n] = (float)tanh(v);   // fp32 rank key AND feature value
}

// ---------------- per-graph head: fp32 keys, ulp-window tie -> index -------
__global__ __launch_bounds__(256) void head_kernel(const float* __restrict__ x1,
                                                   const float* __restrict__ x2,
                                                   const float* __restrict__ x3f,
                                                   const float* __restrict__ c1w,
                                                   const float* __restrict__ c1b,
                                                   const float* __restrict__ c2w,
                                                   const float* __restrict__ c2b,
                                                   const float* __restrict__ l1w,
                                                   const float* __restrict__ l1b,
                                                   const float* __restrict__ l2w,
                                                   const float* __restrict__ l2b,
                                                   float* __restrict__ out) {
    int g = blockIdx.x;
    size_t nbase = (size_t)g * N_;
    __shared__ float sv[N_];
    __shared__ int   topk[K_];
    __shared__ float pooled[K_][LAT_];
    __shared__ float c1[16][K_];
    __shared__ float mp[16][10];
    __shared__ float c2[32 * 6];
    __shared__ float l1[128];

    for (int i = threadIdx.x; i < K_; i += 256) topk[i] = i;  // fallback
    for (int i = threadIdx.x; i < N_; i += 256) sv[i] = x3f[nbase + i];
    __syncthreads();

    // top-K descending on fp32 keys. Pairs within ~1.5 ulp (relative) are
    // treated as np-fp32 ties -> stable order (lower index first). Rationale:
    // np's fp32 accumulation noise (~10 ulp) collapses sub-ulp true gaps to
    // one representable; its stable argsort then orders by index.
    for (int i = threadIdx.x; i < N_; i += 256) {
        float v = sv[i];
        int rank = 0;
        for (int j = 0; j < N_; ++j) {
            float u = sv[j];
            float mag = fmaxf(fabsf(u), fabsf(v));
            bool tie = fabsf(u - v) <= EPS_REL * mag;
            bool beats = tie ? (j < i) : (u > v);
            rank += beats;
        }
        if (rank < K_) topk[rank] = i;
    }
    __syncthreads();

    for (int i = threadIdx.x; i < K_ * LAT_; i += 256) {
        int k = i / LAT_, c = i % LAT_;
        int node = topk[k];
        float f;
        if (c < HID_)            f = x1[(nbase + node) * HID_ + c];
        else if (c < 2 * HID_)   f = x2[(nbase + node) * HID_ + (c - HID_)];
        else                     f = sv[node];
        pooled[k][c] = f;
    }
    __syncthreads();

    for (int i = threadIdx.x; i < 16 * K_; i += 256) {
        int o = i / K_, k = i % K_;
        float acc = c1b[o];
        for (int c = 0; c < LAT_; ++c) acc += pooled[k][c] * c1w[o * LAT_ + c];
        c1[o][k] = fmaxf(acc, 0.f);
    }
    __syncthreads();

    for (int i = threadIdx.x; i < 160; i += 256) {
        int o = i / 10, t = i % 10;
        mp[o][t] = fmaxf(c1[o][2 * t], c1[o][2 * t + 1]);
    }
    __syncthreads();

    for (int i = threadIdx.x; i < 192; i += 256) {
        int o = i / 6, t = i % 6;
        float acc = c2b[o];
        for (int ic = 0; ic < 16; ++ic)
#pragma unroll
            for (int j = 0; j < 5; ++j)
                acc += mp[ic][t + j] * c2w[(o * 16 + ic) * 5 + j];
        c2[o * 6 + t] = fmaxf(acc, 0.f);
    }
    __syncthreads();

    for (int i = threadIdx.x; i < 128; i += 256) {
        float acc = l1b[i];
        for (int c = 0; c < 192; ++c) acc += c2[c] * l1w[c * 128 + i];
        l1[i] = fmaxf(acc, 0.f);
    }
    __syncthreads();

    for (int i = threadIdx.x; i < 2; i += 256) {
        float acc = l2b[i];
        for (int c = 0; c < 128; ++c) acc += l1[c] * l2w[c * 2 + i];
        out[g * 2 + i] = acc;
    }
}

extern "C" void kernel_launch(void* const* d_in, const int* in_sizes, int n_in,
                              void* d_out, int out_size, void* d_ws, size_t ws_size,
                              hipStream_t stream) {
    const float* x   = (const float*)d_in[0];
    const int*   ei  = (const int*)d_in[1];
    const float* W0  = (const float*)d_in[3];
    const float* b0  = (const float*)d_in[4];
    const float* W1  = (const float*)d_in[5];
    const float* b1  = (const float*)d_in[6];
    const float* W2  = (const float*)d_in[7];
    const float* b2  = (const float*)d_in[8];
    const float* c1w = (const float*)d_in[9];
    const float* c1b = (const float*)d_in[10];
    const float* c2w = (const float*)d_in[11];
    const float* c2b = (const float*)d_in[12];
    const float* l1w = (const float*)d_in[13];
    const float* l1b = (const float*)d_in[14];
    const float* l2w = (const float*)d_in[15];
    const float* l2b = (const float*)d_in[16];

    const int* src = ei;
    const int* dst = ei + (size_t)G_ * EG_;

    char* wsb = (char*)d_ws;
    unsigned short* srcl = (unsigned short*)wsb; wsb += (size_t)G_ * EG_ * 2;
    int* gstart = (int*)wsb;                     wsb += (size_t)G_ * (N_ + 1) * 4;
    double* disd = (double*)wsb;                 wsb += (size_t)NN_ * 8;
    float*  x3f  = (float*)wsb;                  wsb += (size_t)NN_ * 4;
    float*  x1f  = (float*)wsb;                  wsb += (size_t)NN_ * HID_ * 4;
    float*  x2f  = (float*)wsb;                  wsb += (size_t)NN_ * HID_ * 4;

    csr2_kernel<<<G_, 512, 0, stream>>>(src, dst, srcl, gstart, disd);
    gcn_kernel<CIN_><<<G_, 512, 0, stream>>>(x, W0, b0, srcl, gstart, disd, x1f);
    gcn_kernel<HID_><<<G_, 512, 0, stream>>>(x1f, W1, b1, srcl, gstart, disd, x2f);
    gcn3_kernel<<<G_, 512, 0, stream>>>(x2f, W2, b2, srcl, gstart, disd, x3f);
    head_kernel<<<G_, 256, 0, stream>>>(x1f, x2f, x3f, c1w, c1b, c2w, c2b,
                                        l1w, l1b, l2w, l2b, (float*)d_out);
}